// Round 1
// baseline (3736.584 us; speedup 1.0000x reference)
//
#include <hip/hip_runtime.h>

// BezierAlign: input (N=2, C=256, H=160, W=160) fp32, rois (R, 17) fp32.
// out (R, C, 16, 64) fp32. SPATIAL_SCALE=0.25, SAMPLING_RATIO=2, ALIGNED.
// Structure: one block per (r, ph); lane = pw (OUT_W==64==wave size) so output
// stores coalesce and gather lanes walk along the curve; 4 waves split the 256
// channels. Geometry (16 offsets + 16 weights per lane) computed once, reused
// for all channels.

#define OUT_H 16
#define OUT_W 64
#define SPATIAL_SCALE 0.25f
#define C_DIM 256
#define H_DIM 160
#define W_DIM 160

__global__ __launch_bounds__(256) void bezier_align_kernel(
    const float* __restrict__ input, const float* __restrict__ rois,
    float* __restrict__ out) {
  const int blk  = blockIdx.x;
  const int r    = blk >> 4;   // / OUT_H
  const int ph   = blk & 15;   // % OUT_H
  const int lane = threadIdx.x & 63;
  const int wave = threadIdx.x >> 6;
  const int pw   = lane;

  const float* roi = rois + (size_t)r * 17;
  const int n = (int)roi[0];

  float px[8], py[8];
#pragma unroll
  for (int k = 0; k < 8; ++k) {
    px[k] = roi[1 + 2 * k] * SPATIAL_SCALE;
    py[k] = roi[2 + 2 * k] * SPATIAL_SCALE;
  }

  // Bezier at t = pw / OUT_W along top (pts 0..3) and bottom (pts 4..7).
  const float u  = (float)pw * (1.0f / OUT_W);
  const float vv = (float)ph * (1.0f / OUT_H);
  const float mt = 1.0f - u;
  const float b0 = mt * mt * mt;
  const float b1 = 3.0f * u * mt * mt;
  const float b2 = 3.0f * u * u * mt;
  const float b3 = u * u * u;
  const float x0 = b0 * px[0] + b1 * px[1] + b2 * px[2] + b3 * px[3];
  const float y0 = b0 * py[0] + b1 * py[1] + b2 * py[2] + b3 * py[3];
  const float x1 = b0 * px[4] + b1 * px[5] + b2 * px[6] + b3 * px[7];
  const float y1 = b0 * py[4] + b1 * py[5] + b2 * py[6] + b3 * py[7];

  const float xc = x1 * vv + x0 * (1.0f - vv) - 0.5f;  // ALIGNED offset
  const float yc = y1 * vv + y0 * (1.0f - vv) - 0.5f;

  const float roi_w = fmaxf(fabsf(px[0] - px[3]), fabsf(px[4] - px[7]));
  const float roi_h = fmaxf(fabsf(py[0] - py[3]), fabsf(py[4] - py[7]));
  const float bin_h = roi_h * (1.0f / OUT_H);
  const float bin_w = roi_w * (1.0f / OUT_W);

  // Per-lane gather plan: 4 samples x 4 corners. /4 averaging folded into
  // the weights; invalid samples get weight 0.
  int   off[16];
  float wgt[16];
#pragma unroll
  for (int s = 0; s < 4; ++s) {
    const int iy = s >> 1, ix = s & 1;
    float y = yc - 0.5f * bin_h + ((float)iy + 0.5f) * bin_h * 0.5f;
    float x = xc - 0.5f * bin_w + ((float)ix + 0.5f) * bin_w * 0.5f;
    const bool valid = (y > -1.0f) && (y < (float)H_DIM) &&
                       (x > -1.0f) && (x < (float)W_DIM);
    y = fmaxf(y, 0.0f);
    x = fmaxf(x, 0.0f);
    int yl = min((int)y, H_DIM - 1);   // y >= 0 so (int) == floor
    int xl = min((int)x, W_DIM - 1);
    const int yh = min(yl + 1, H_DIM - 1);
    const int xh = min(xl + 1, W_DIM - 1);
    if (yl >= H_DIM - 1) y = (float)yl;
    if (xl >= W_DIM - 1) x = (float)xl;
    const float ly = y - (float)yl;
    const float lx = x - (float)xl;
    const float hy = 1.0f - ly;
    const float hx = 1.0f - lx;
    const float vw = valid ? 0.25f : 0.0f;
    wgt[4 * s + 0] = vw * hy * hx;  off[4 * s + 0] = yl * W_DIM + xl;
    wgt[4 * s + 1] = vw * hy * lx;  off[4 * s + 1] = yl * W_DIM + xh;
    wgt[4 * s + 2] = vw * ly * hx;  off[4 * s + 2] = yh * W_DIM + xl;
    wgt[4 * s + 3] = vw * ly * lx;  off[4 * s + 3] = yh * W_DIM + xh;
  }

  const size_t HW = (size_t)H_DIM * W_DIM;
  const float* base = input + (size_t)n * C_DIM * HW;
  float* outp = out + (((size_t)r * C_DIM) * OUT_H + ph) * OUT_W + pw;

  // Wave w handles channels [w*64, w*64+64).
  const int c0 = wave * 64;
#pragma unroll 2
  for (int cc = 0; cc < 64; ++cc) {
    const int c = c0 + cc;
    const float* p = base + (size_t)c * HW;
    float acc = 0.0f;
#pragma unroll
    for (int k = 0; k < 16; ++k) acc = fmaf(wgt[k], p[off[k]], acc);
    outp[(size_t)c * (OUT_H * OUT_W)] = acc;
  }
}

extern "C" void kernel_launch(void* const* d_in, const int* in_sizes, int n_in,
                              void* d_out, int out_size, void* d_ws, size_t ws_size,
                              hipStream_t stream) {
  const float* input = (const float*)d_in[0];
  const float* rois  = (const float*)d_in[1];
  float* out = (float*)d_out;
  const int R = in_sizes[1] / 17;  // 256 for this problem
  bezier_align_kernel<<<dim3(R * OUT_H), dim3(256), 0, stream>>>(input, rois, out);
}

// Round 2
// 502.527 us; speedup vs baseline: 7.4356x; 7.4356x over previous
//
#include <hip/hip_runtime.h>

// BezierAlign, R2: NCHW->NHWC transpose into d_ws, then coalesced channel-major
// gather. Block = (r, ph); wave0 builds the 64pw x 16corner (offset,weight)
// table in LDS; each thread accumulates 4 channels (float4) x 16 pw with
// wave-uniform gather offsets (readfirstlane -> SGPR base). Output transposed
// through LDS for pw-contiguous coalesced stores.

#define OUT_H 16
#define OUT_W 64
#define SPATIAL_SCALE 0.25f
#define C_DIM 256
#define H_DIM 160
#define W_DIM 160
#define HW_DIM (H_DIM * W_DIM)

// ---------- Pass 1: NCHW -> NHWC (per batch: transpose 256 x 25600) ----------
__global__ __launch_bounds__(256) void nchw_to_nhwc(const float* __restrict__ in,
                                                    float* __restrict__ outb) {
  __shared__ float lds[64][65];
  const int b = blockIdx.x;
  const int n = b / 1600;          // 1600 tiles per batch: 4 (c) x 400 (hw)
  const int t = b - n * 1600;
  const int tc = t & 3;
  const int tp = t >> 2;
  const int c0 = tc * 64, p0 = tp * 64;
  const float* A = in + (size_t)n * C_DIM * HW_DIM;
  float* B = outb + (size_t)n * HW_DIM * C_DIM;
  const int j = threadIdx.x & 63;
  const int i0 = threadIdx.x >> 6;
#pragma unroll
  for (int k = 0; k < 16; ++k) {
    const int i = i0 + 4 * k;
    lds[i][j] = A[(size_t)(c0 + i) * HW_DIM + (p0 + j)];   // coalesced along hw
  }
  __syncthreads();
#pragma unroll
  for (int k = 0; k < 16; ++k) {
    const int jj = i0 + 4 * k;
    B[(size_t)(p0 + jj) * C_DIM + (c0 + j)] = lds[j][jj];  // coalesced along c
  }
}

// ---------- Pass 2: gather from NHWC ----------
__global__ __launch_bounds__(256) void bezier_gather(const float* __restrict__ feat,
                                                     const float* __restrict__ rois,
                                                     float* __restrict__ out) {
  __shared__ int2 s_geo[OUT_W * 16];     // {pos, weight-bits} per (pw, corner)
  __shared__ float s_tile[64][65];       // store-transpose tile (c_loc x pw)

  const int blk = blockIdx.x;
  const int r = blk >> 4;
  const int ph = blk & 15;
  const int tid = threadIdx.x;
  const int lane = tid & 63;
  const int q = tid >> 6;                // wave id = pw quarter

  const float* roi = rois + (size_t)r * 17;
  const int n = (int)roi[0];

  if (tid < 64) {
    const int pw = tid;
    float px[8], py[8];
#pragma unroll
    for (int k = 0; k < 8; ++k) {
      px[k] = roi[1 + 2 * k] * SPATIAL_SCALE;
      py[k] = roi[2 + 2 * k] * SPATIAL_SCALE;
    }
    const float u = (float)pw * (1.0f / OUT_W);
    const float vv = (float)ph * (1.0f / OUT_H);
    const float mt = 1.0f - u;
    const float b0 = mt * mt * mt;
    const float b1 = 3.0f * u * mt * mt;
    const float b2 = 3.0f * u * u * mt;
    const float b3 = u * u * u;
    const float x0 = b0 * px[0] + b1 * px[1] + b2 * px[2] + b3 * px[3];
    const float y0 = b0 * py[0] + b1 * py[1] + b2 * py[2] + b3 * py[3];
    const float x1 = b0 * px[4] + b1 * px[5] + b2 * px[6] + b3 * px[7];
    const float y1 = b0 * py[4] + b1 * py[5] + b2 * py[6] + b3 * py[7];
    const float xc = x1 * vv + x0 * (1.0f - vv) - 0.5f;
    const float yc = y1 * vv + y0 * (1.0f - vv) - 0.5f;
    const float roi_w = fmaxf(fabsf(px[0] - px[3]), fabsf(px[4] - px[7]));
    const float roi_h = fmaxf(fabsf(py[0] - py[3]), fabsf(py[4] - py[7]));
    const float bin_h = roi_h * (1.0f / OUT_H);
    const float bin_w = roi_w * (1.0f / OUT_W);
#pragma unroll
    for (int s = 0; s < 4; ++s) {
      const int iy = s >> 1, ix = s & 1;
      float y = yc - 0.5f * bin_h + ((float)iy + 0.5f) * bin_h * 0.5f;
      float x = xc - 0.5f * bin_w + ((float)ix + 0.5f) * bin_w * 0.5f;
      const bool valid = (y > -1.0f) && (y < (float)H_DIM) &&
                         (x > -1.0f) && (x < (float)W_DIM);
      y = fmaxf(y, 0.0f);
      x = fmaxf(x, 0.0f);
      int yl = min((int)y, H_DIM - 1);
      int xl = min((int)x, W_DIM - 1);
      const int yh = min(yl + 1, H_DIM - 1);
      const int xh = min(xl + 1, W_DIM - 1);
      if (yl >= H_DIM - 1) y = (float)yl;
      if (xl >= W_DIM - 1) x = (float)xl;
      const float ly = y - (float)yl;
      const float lx = x - (float)xl;
      const float hy = 1.0f - ly;
      const float hx = 1.0f - lx;
      const float vw = valid ? 0.25f : 0.0f;
      s_geo[pw * 16 + 4 * s + 0] = make_int2(yl * W_DIM + xl, __float_as_int(vw * hy * hx));
      s_geo[pw * 16 + 4 * s + 1] = make_int2(yl * W_DIM + xh, __float_as_int(vw * hy * lx));
      s_geo[pw * 16 + 4 * s + 2] = make_int2(yh * W_DIM + xl, __float_as_int(vw * ly * hx));
      s_geo[pw * 16 + 4 * s + 3] = make_int2(yh * W_DIM + xh, __float_as_int(vw * ly * lx));
    }
  }
  __syncthreads();

  const float* fb = feat + (size_t)n * HW_DIM * C_DIM;
  const int voff = lane * 4;             // this thread's 4-channel base (floats)
  const int pw0 = q * 16;

  float4 acc[16];
#pragma unroll
  for (int j = 0; j < 16; ++j) acc[j] = make_float4(0.f, 0.f, 0.f, 0.f);

#pragma unroll
  for (int j = 0; j < 16; ++j) {
#pragma unroll
    for (int k = 0; k < 16; ++k) {
      const int2 g = s_geo[(pw0 + j) * 16 + k];
      const int pos = __builtin_amdgcn_readfirstlane(g.x);   // wave-uniform
      const float w = __int_as_float(__builtin_amdgcn_readfirstlane(g.y));
      const float4 v = *(const float4*)(fb + (size_t)pos * C_DIM + voff);
      acc[j].x = fmaf(w, v.x, acc[j].x);
      acc[j].y = fmaf(w, v.y, acc[j].y);
      acc[j].z = fmaf(w, v.z, acc[j].z);
      acc[j].w = fmaf(w, v.w, acc[j].w);
    }
  }

  // Store: 4 rounds of 64 channels, LDS-transposed for pw-contiguous stores.
  const int cg = lane >> 4;              // which 64-ch group this thread holds
  const int clb = (lane & 15) * 4;       // c offset within that group
#pragma unroll 1
  for (int g = 0; g < 4; ++g) {
    __syncthreads();
    if (cg == g) {
#pragma unroll
      for (int j = 0; j < 16; ++j) {
        s_tile[clb + 0][pw0 + j] = acc[j].x;
        s_tile[clb + 1][pw0 + j] = acc[j].y;
        s_tile[clb + 2][pw0 + j] = acc[j].z;
        s_tile[clb + 3][pw0 + j] = acc[j].w;
      }
    }
    __syncthreads();
    float* ob = out + (((size_t)r * C_DIM + g * 64) * OUT_H + ph) * OUT_W;
#pragma unroll
    for (int kk = 0; kk < 16; ++kk) {
      const int cl = q + 4 * kk;
      ob[(size_t)cl * (OUT_H * OUT_W) + lane] = s_tile[cl][lane];  // 256B/wave
    }
  }
}

// ---------- Fallback (R1 kernel) if workspace too small for NHWC copy ----------
__global__ __launch_bounds__(256) void bezier_align_fallback(
    const float* __restrict__ input, const float* __restrict__ rois,
    float* __restrict__ out) {
  const int blk = blockIdx.x;
  const int r = blk >> 4;
  const int ph = blk & 15;
  const int lane = threadIdx.x & 63;
  const int wave = threadIdx.x >> 6;
  const int pw = lane;
  const float* roi = rois + (size_t)r * 17;
  const int n = (int)roi[0];
  float px[8], py[8];
#pragma unroll
  for (int k = 0; k < 8; ++k) {
    px[k] = roi[1 + 2 * k] * SPATIAL_SCALE;
    py[k] = roi[2 + 2 * k] * SPATIAL_SCALE;
  }
  const float u = (float)pw * (1.0f / OUT_W);
  const float vv = (float)ph * (1.0f / OUT_H);
  const float mt = 1.0f - u;
  const float b0 = mt * mt * mt;
  const float b1 = 3.0f * u * mt * mt;
  const float b2 = 3.0f * u * u * mt;
  const float b3 = u * u * u;
  const float x0 = b0 * px[0] + b1 * px[1] + b2 * px[2] + b3 * px[3];
  const float y0 = b0 * py[0] + b1 * py[1] + b2 * py[2] + b3 * py[3];
  const float x1 = b0 * px[4] + b1 * px[5] + b2 * px[6] + b3 * px[7];
  const float y1 = b0 * py[4] + b1 * py[5] + b2 * py[6] + b3 * py[7];
  const float xc = x1 * vv + x0 * (1.0f - vv) - 0.5f;
  const float yc = y1 * vv + y0 * (1.0f - vv) - 0.5f;
  const float roi_w = fmaxf(fabsf(px[0] - px[3]), fabsf(px[4] - px[7]));
  const float roi_h = fmaxf(fabsf(py[0] - py[3]), fabsf(py[4] - py[7]));
  const float bin_h = roi_h * (1.0f / OUT_H);
  const float bin_w = roi_w * (1.0f / OUT_W);
  int off[16];
  float wgt[16];
#pragma unroll
  for (int s = 0; s < 4; ++s) {
    const int iy = s >> 1, ix = s & 1;
    float y = yc - 0.5f * bin_h + ((float)iy + 0.5f) * bin_h * 0.5f;
    float x = xc - 0.5f * bin_w + ((float)ix + 0.5f) * bin_w * 0.5f;
    const bool valid = (y > -1.0f) && (y < (float)H_DIM) &&
                       (x > -1.0f) && (x < (float)W_DIM);
    y = fmaxf(y, 0.0f);
    x = fmaxf(x, 0.0f);
    int yl = min((int)y, H_DIM - 1);
    int xl = min((int)x, W_DIM - 1);
    const int yh = min(yl + 1, H_DIM - 1);
    const int xh = min(xl + 1, W_DIM - 1);
    if (yl >= H_DIM - 1) y = (float)yl;
    if (xl >= W_DIM - 1) x = (float)xl;
    const float ly = y - (float)yl;
    const float lx = x - (float)xl;
    const float hy = 1.0f - ly;
    const float hx = 1.0f - lx;
    const float vw = valid ? 0.25f : 0.0f;
    wgt[4 * s + 0] = vw * hy * hx;  off[4 * s + 0] = yl * W_DIM + xl;
    wgt[4 * s + 1] = vw * hy * lx;  off[4 * s + 1] = yl * W_DIM + xh;
    wgt[4 * s + 2] = vw * ly * hx;  off[4 * s + 2] = yh * W_DIM + xl;
    wgt[4 * s + 3] = vw * ly * lx;  off[4 * s + 3] = yh * W_DIM + xh;
  }
  const size_t HW = (size_t)HW_DIM;
  const float* base = input + (size_t)n * C_DIM * HW;
  float* outp = out + (((size_t)r * C_DIM) * OUT_H + ph) * OUT_W + pw;
  const int c0 = wave * 64;
#pragma unroll 2
  for (int cc = 0; cc < 64; ++cc) {
    const int c = c0 + cc;
    const float* p = base + (size_t)c * HW;
    float acc = 0.0f;
#pragma unroll
    for (int k = 0; k < 16; ++k) acc = fmaf(wgt[k], p[off[k]], acc);
    outp[(size_t)c * (OUT_H * OUT_W)] = acc;
  }
}

extern "C" void kernel_launch(void* const* d_in, const int* in_sizes, int n_in,
                              void* d_out, int out_size, void* d_ws, size_t ws_size,
                              hipStream_t stream) {
  const float* input = (const float*)d_in[0];
  const float* rois = (const float*)d_in[1];
  float* out = (float*)d_out;
  const int R = in_sizes[1] / 17;
  const int N = in_sizes[0] / (C_DIM * HW_DIM);
  const size_t need = (size_t)in_sizes[0] * sizeof(float);
  if (ws_size >= need) {
    float* nhwc = (float*)d_ws;
    nchw_to_nhwc<<<dim3(N * 1600), dim3(256), 0, stream>>>(input, nhwc);
    bezier_gather<<<dim3(R * OUT_H), dim3(256), 0, stream>>>(nhwc, rois, out);
  } else {
    bezier_align_fallback<<<dim3(R * OUT_H), dim3(256), 0, stream>>>(input, rois, out);
  }
}